// Round 13
// baseline (141.414 us; speedup 1.0000x reference)
//
#include <hip/hip_runtime.h>
#include <stdint.h>
#include <math.h>

// MulHeadAttn on MI355X. B=2, C=1024, E=1024, head_dim(H)=16, n_heads(HD)=64.
// cast(fp32->bf16, Wq pre-scaled 0.25*log2e) -> fused QKV bf16-MFMA GEMM
// (128x128 tile, global_load_lds dbuf) -> MFMA flash attention
// (R21: q-tile 64 / grid 2048 RETRY with lb(256,4) — R19's identical body
//  spilled only because lb(256,8) capped VGPR at 64 (settled 32, 52MB
//  scratch). Natural allocation ~52 VGPR <= 64 -> 8 blocks/CU by LDS
//  (19456B) + VGPR + grid. Occupancy was the untested lever: attn is
//  latency-bound at Occ 31% / MfmaUtil 13% / VALUBusy 26%.)
// -> bf16-MFMA O-projection (64x64 tile, 512 blocks = 2/CU).

typedef __bf16   bf16x8 __attribute__((ext_vector_type(8)));
typedef float    f32x4  __attribute__((ext_vector_type(4)));

__device__ __forceinline__ unsigned short f2bf(float f) {
    unsigned int u = __float_as_uint(f);
    u += 0x7FFFu + ((u >> 16) & 1u);         // round-to-nearest-even
    return (unsigned short)(u >> 16);
}

// async global->LDS, 16 bytes per lane (dest = wave-uniform base + lane*16)
__device__ __forceinline__ void gl16(const unsigned short* g, unsigned short* l) {
    __builtin_amdgcn_global_load_lds(
        (const __attribute__((address_space(1))) unsigned int*)g,
        (__attribute__((address_space(3))) unsigned int*)l, 16, 0, 0);
}

// ---------------------------------------------------------------- cast ----
// z=0,1: halves of x; z=2: Wq scaled 0.25*log2(e) (softmax scale folded into
// the exp2 domain); z=3..5: Wk, Wv, Wo.
__global__ __launch_bounds__(256) void cast_to_bf16(
    const float* __restrict__ x,
    const float* __restrict__ w0, const float* __restrict__ w1,
    const float* __restrict__ w2, const float* __restrict__ w3,
    unsigned short* __restrict__ xb,
    unsigned short* __restrict__ b0, unsigned short* __restrict__ b1,
    unsigned short* __restrict__ b2, unsigned short* __restrict__ b3)
{
    const int z = blockIdx.y;
    const float* src;
    unsigned short* dst;
    size_t off = 0;
    float sc = 1.f;
    if (z < 2)       { src = x;  dst = xb; off = (size_t)z << 20; }
    else if (z == 2) { src = w0; dst = b0; sc = 0.36067376022224085f; } // 0.25*log2e
    else if (z == 3) { src = w1; dst = b1; }
    else if (z == 4) { src = w2; dst = b2; }
    else             { src = w3; dst = b3; }
    const size_t i = off + ((size_t)blockIdx.x * 256 + threadIdx.x) * 4;
    const float4 v = *(const float4*)(src + i);
    *(ushort4*)(dst + i) = make_ushort4(f2bf(v.x * sc), f2bf(v.y * sc),
                                        f2bf(v.z * sc), f2bf(v.w * sc));
}

// ------------------------------------------------------- GEMM 128x128 ----
// QKV GEMM: 128x128 tile, BK=32, 4 waves each computing a 64x64 sub-tile
// via acc[4][4] of 16x16x32 MFMA. global_load_lds width-16, double-buffered.
__global__ __launch_bounds__(256) void gemm128_bt_mfma(
    const unsigned short* __restrict__ A,
    const unsigned short* __restrict__ B0, const unsigned short* __restrict__ B1,
    const unsigned short* __restrict__ B2,
    unsigned short* __restrict__ C0, unsigned short* __restrict__ C1,
    unsigned short* __restrict__ C2,
    int M, int N, int K)
{
    const unsigned short* Bm = (blockIdx.z == 0) ? B0 : (blockIdx.z == 1) ? B1 : B2;
    unsigned short* Cm       = (blockIdx.z == 0) ? C0 : (blockIdx.z == 1) ? C1 : C2;

    __shared__ __align__(16) unsigned short As[2][128 * 32];  // 16 KB
    __shared__ __align__(16) unsigned short Bs[2][128 * 32];  // 16 KB

    const int t    = threadIdx.x;
    const int lane = t & 63;
    const int w    = t >> 6;
    const int m0   = blockIdx.y * 128;
    const int n0   = blockIdx.x * 128;
    const int wm   = (w & 1) * 64;
    const int wn   = (w >> 1) * 64;

    const int r0 = t >> 2;
    const int c0 = (t & 3) * 8;
    const unsigned short* Apa = A  + (size_t)(m0 + r0) * K + c0;
    const unsigned short* Apb = Apa + (size_t)64 * K;
    const unsigned short* Bpa = Bm + (size_t)(n0 + r0) * K + c0;
    const unsigned short* Bpb = Bpa + (size_t)64 * K;
    unsigned short* lA0 = &As[0][w * 512];
    unsigned short* lA1 = &As[0][2048 + w * 512];
    unsigned short* lB0 = &Bs[0][w * 512];
    unsigned short* lB1 = &Bs[0][2048 + w * 512];
    const int bufStr = 128 * 32;

    f32x4 acc[4][4];
#pragma unroll
    for (int i = 0; i < 4; ++i)
#pragma unroll
        for (int j = 0; j < 4; ++j) acc[i][j] = (f32x4){0.f, 0.f, 0.f, 0.f};

    const int fm = lane & 15;
    const int kg = lane >> 4;

    gl16(Apa, lA0);
    gl16(Apb, lA1);
    gl16(Bpa, lB0);
    gl16(Bpb, lB1);

    int cur = 0;
    for (int k0 = 0; k0 < K; k0 += 32) {
        __syncthreads();

        if (k0 + 32 < K) {
            const int nb = (cur ^ 1);
            gl16(Apa + k0 + 32, lA0 + nb * bufStr);
            gl16(Apb + k0 + 32, lA1 + nb * bufStr);
            gl16(Bpa + k0 + 32, lB0 + nb * bufStr);
            gl16(Bpb + k0 + 32, lB1 + nb * bufStr);
        }

        const unsigned short* Ab = &As[cur][0];
        const unsigned short* Bb = &Bs[cur][0];
        bf16x8 af[4], bfr[4];
#pragma unroll
        for (int im = 0; im < 4; ++im)
            af[im] = *(const bf16x8*)&Ab[(wm + im * 16 + fm) * 32 + kg * 8];
#pragma unroll
        for (int in = 0; in < 4; ++in)
            bfr[in] = *(const bf16x8*)&Bb[(wn + in * 16 + fm) * 32 + kg * 8];
#pragma unroll
        for (int im = 0; im < 4; ++im)
#pragma unroll
            for (int in = 0; in < 4; ++in)
                acc[im][in] = __builtin_amdgcn_mfma_f32_16x16x32_bf16(
                    af[im], bfr[in], acc[im][in], 0, 0, 0);

        cur ^= 1;
    }

#pragma unroll
    for (int im = 0; im < 4; ++im) {
#pragma unroll
        for (int in = 0; in < 4; ++in) {
            const int row = m0 + wm + im * 16 + kg * 4;
            const int col = n0 + wn + in * 16 + fm;
#pragma unroll
            for (int r = 0; r < 4; ++r)
                Cm[(size_t)(row + r) * N + col] = f2bf(acc[im][in][r]);
        }
    }
}

// --------------------------------------------------------- GEMM 64x64 ----
// O-projection: 64x64 tile -> 512 blocks = 2 blocks/CU (barrier drains of
// one block overlap the other block's compute; at 1/CU they stalled the CU).
__global__ __launch_bounds__(256) void gemm64_bt_mfma(
    const unsigned short* __restrict__ A, const unsigned short* __restrict__ Bm,
    float* __restrict__ Cm, int M, int N, int K)
{
    __shared__ __align__(16) unsigned short As[2][64 * 32];   // 8 KB
    __shared__ __align__(16) unsigned short Bs[2][64 * 32];   // 8 KB

    const int t    = threadIdx.x;
    const int lane = t & 63;
    const int w    = t >> 6;
    const int m0   = blockIdx.y * 64;
    const int n0   = blockIdx.x * 64;
    const int wm   = (w & 1) * 32;
    const int wn   = (w >> 1) * 32;

    const int r0 = t >> 2;
    const int c0 = (t & 3) * 8;
    const unsigned short* Apa = A  + (size_t)(m0 + r0) * K + c0;
    const unsigned short* Bpa = Bm + (size_t)(n0 + r0) * K + c0;
    unsigned short* ldsA = &As[0][w * 512];
    unsigned short* ldsB = &Bs[0][w * 512];
    const int bufStr = 64 * 32;

    f32x4 acc[2][2];
#pragma unroll
    for (int i = 0; i < 2; ++i)
#pragma unroll
        for (int j = 0; j < 2; ++j) acc[i][j] = (f32x4){0.f, 0.f, 0.f, 0.f};

    const int fm = lane & 15;
    const int kg = lane >> 4;

    gl16(Apa, ldsA);
    gl16(Bpa, ldsB);

    int cur = 0;
    for (int k0 = 0; k0 < K; k0 += 32) {
        __syncthreads();

        if (k0 + 32 < K) {
            const int nb = (cur ^ 1);
            gl16(Apa + k0 + 32, ldsA + nb * bufStr);
            gl16(Bpa + k0 + 32, ldsB + nb * bufStr);
        }

        const unsigned short* Ab = &As[cur][0];
        const unsigned short* Bb = &Bs[cur][0];
        bf16x8 af[2], bfr[2];
#pragma unroll
        for (int im = 0; im < 2; ++im)
            af[im] = *(const bf16x8*)&Ab[(wm + im * 16 + fm) * 32 + kg * 8];
#pragma unroll
        for (int in = 0; in < 2; ++in)
            bfr[in] = *(const bf16x8*)&Bb[(wn + in * 16 + fm) * 32 + kg * 8];
#pragma unroll
        for (int im = 0; im < 2; ++im)
#pragma unroll
            for (int in = 0; in < 2; ++in)
                acc[im][in] = __builtin_amdgcn_mfma_f32_16x16x32_bf16(
                    af[im], bfr[in], acc[im][in], 0, 0, 0);

        cur ^= 1;
    }

#pragma unroll
    for (int im = 0; im < 2; ++im) {
#pragma unroll
        for (int in = 0; in < 2; ++in) {
            const int row = m0 + wm + im * 16 + kg * 4;
            const int col = n0 + wn + in * 16 + fm;
#pragma unroll
            for (int r = 0; r < 4; ++r)
                Cm[(size_t)(row + r) * N + col] = acc[im][in][r];
        }
    }
}

// ----------------------------------------------------------- attention ----
// R21: keys-split, q-tile 64, grid 2048 (1D, XCD-aware). lb(256,4): VGPR
// cap 128 -> allocator free, expected ~52 (persistent: aq[4]+oacc[4]+lp[4]
// = 36 + temps). At VGPR<=64: 8 blocks/CU (LDS 19456B, grid 2048/256=8).
// Block = one (b,hd) x 64 q-rows, 4 waves; wave wv owns keys
// [wv*32,wv*32+32) x all 64 q-rows; barrier-free k-loop (LDS wave-private).
// P-in-register via permuted key axis (verified R16). Red overlay 256x17
// f32 = 17408 B fits inside the 19456 B live footprint.
#define KROWS 40    // Ks row stride (u16): 16 real d + 24 pad (80 B)
#define VROWS 72    // VsT row stride (u16): 32 perm cols + 40 pad (144 B)

__global__ __launch_bounds__(256, 4) void attn_mfma(
    const unsigned short* __restrict__ Qb, const unsigned short* __restrict__ Kb,
    const unsigned short* __restrict__ Vb, unsigned short* __restrict__ Ob)
{
    __shared__ __align__(16) unsigned char smem[19456];

    const int t    = threadIdx.x;
    const int lane = t & 63;
    const int wv   = t >> 6;
    const int fm   = lane & 15;
    const int kg   = lane >> 4;

    // XCD-aware inverse mapping: blk = xcd + 8*i round-robins across XCDs.
    // All 16 q-tiles of one bh AND the 4 heads sharing each 128B line on
    // one XCD. Bijective over 2048.
    const int blk = blockIdx.x;
    const int xcd = blk & 7;
    const int i_  = blk >> 3;
    const int qt  = i_ & 15;
    const int hdg = (i_ >> 4) & 3;
    const int gs  = (i_ >> 6) & 1;
    const int bb  = (i_ >> 7) & 1;
    const int hd  = (xcd + gs * 8) * 4 + hdg;
    const size_t base = ((size_t)bb << 20) + (size_t)hd * 16;
    const int q0 = qt * 64;
    const int wk = wv * 32;          // wave's key offset within tile

    unsigned short* Ks  = (unsigned short*)(smem + wv * 2560);
    unsigned short* VsT = (unsigned short*)(smem + 10240 + wv * 2304);
    float*          Red = (float*)smem;

    // staging roles: lane covers (key2 = lane>>1, half = lane&1)
    const int key2 = lane >> 1, half = lane & 1;
    // permuted V column for key2: slot where PV expects this key
    const int vcol = ((key2 & 15) >> 2) * 8 + (key2 & 3) + ((key2 >> 4) << 2);

    // Q fragments (B-operand): row q0+m*16+fm, k=kg*8 (zero for kg>=2)
    union { uint4 u; bf16x8 h; } zz; zz.u = make_uint4(0, 0, 0, 0);
    bf16x8 aq[4];
#pragma unroll
    for (int m = 0; m < 4; ++m) {
        if (kg < 2)
            aq[m] = *(const bf16x8*)(Qb + base +
                     (size_t)(q0 + m * 16 + fm) * 1024 + kg * 8);
        else
            aq[m] = zz.h;
    }

    f32x4 oacc[4];
    float lp[4];
#pragma unroll
    for (int m = 0; m < 4; ++m) {
        oacc[m] = (f32x4){0.f, 0.f, 0.f, 0.f};
        lp[m] = 0.f;
    }

    for (int kt = 0; kt < 1024; kt += 128) {
        // ---- stage K (coalesced 16B, b128 LDS write) + V (perm scatter)
        {
            const uint4 kd = *(const uint4*)(Kb + base +
                              (size_t)(kt + wk + key2) * 1024 + half * 8);
            *(uint4*)&Ks[key2 * KROWS + half * 8] = kd;
            const uint4 vd = *(const uint4*)(Vb + base +
                              (size_t)(kt + wk + key2) * 1024 + half * 8);
            const unsigned short* pv = (const unsigned short*)&vd;
#pragma unroll
            for (int d = 0; d < 8; ++d)
                VsT[(half * 8 + d) * VROWS + vcol] = pv[d];
        }

        // ---- K fragments (A-operand) from LDS: row fm / 16+fm, k=kg*8
        bf16x8 bk0 = zz.h, bk1 = zz.h;
        if (kg < 2) {
            bk0 = *(const bf16x8*)&Ks[fm * KROWS + kg * 8];
            bk1 = *(const bf16x8*)&Ks[(16 + fm) * KROWS + kg * 8];
        }

        // ---- V fragment (B-operand, perm cols): row d=fm, slots kg*8..+8
        const bf16x8 bv = *(const bf16x8*)&VsT[fm * VROWS + kg * 8];

        // ---- QK -> exp2 -> in-register P -> PV (all per-lane)
#pragma unroll
        for (int m = 0; m < 4; ++m) {
            f32x4 s0 = __builtin_amdgcn_mfma_f32_16x16x32_bf16(
                bk0, aq[m], (f32x4){0.f, 0.f, 0.f, 0.f}, 0, 0, 0);
            f32x4 s1 = __builtin_amdgcn_mfma_f32_16x16x32_bf16(
                bk1, aq[m], (f32x4){0.f, 0.f, 0.f, 0.f}, 0, 0, 0);
            const float p0 = __builtin_amdgcn_exp2f(s0[0]);
            const float p1 = __builtin_amdgcn_exp2f(s0[1]);
            const float p2 = __builtin_amdgcn_exp2f(s0[2]);
            const float p3 = __builtin_amdgcn_exp2f(s0[3]);
            const float p4 = __builtin_amdgcn_exp2f(s1[0]);
            const float p5 = __builtin_amdgcn_exp2f(s1[1]);
            const float p6 = __builtin_amdgcn_exp2f(s1[2]);
            const float p7 = __builtin_amdgcn_exp2f(s1[3]);
            lp[m] += ((p0 + p1) + (p2 + p3)) + ((p4 + p5) + (p6 + p7));
            bf16x8 aph;
            aph[0] = (__bf16)p0; aph[1] = (__bf16)p1;
            aph[2] = (__bf16)p2; aph[3] = (__bf16)p3;
            aph[4] = (__bf16)p4; aph[5] = (__bf16)p5;
            aph[6] = (__bf16)p6; aph[7] = (__bf16)p7;
            oacc[m] = __builtin_amdgcn_mfma_f32_16x16x32_bf16(
                aph, bv, oacc[m], 0, 0, 0);
        }
    }

    // l: sum the 4 kg-group partials -> every lane holds l_wave[q=m*16+fm]
#pragma unroll
    for (int m = 0; m < 4; ++m) {
        lp[m] += __shfl_xor(lp[m], 16, 64);
        lp[m] += __shfl_xor(lp[m], 32, 64);
    }

    __syncthreads();   // all waves done with Ks/VsT -> overlay Red
#pragma unroll
    for (int m = 0; m < 4; ++m) {
#pragma unroll
        for (int r = 0; r < 4; ++r)
            Red[((wv * 64) + m * 16 + kg * 4 + r) * 17 + fm] = oacc[m][r];
        if (kg == 0)
            Red[((wv * 64) + m * 16 + fm) * 17 + 16] = lp[m];
    }
    __syncthreads();

    // wave wv finalizes q-rows [wv*16, wv*16+16)
#pragma unroll
    for (int r = 0; r < 4; ++r) {
        const int q = wv * 16 + kg * 4 + r;
        const float o = Red[q * 17 + fm]        + Red[(64 + q) * 17 + fm] +
                        Red[(128 + q) * 17 + fm] + Red[(192 + q) * 17 + fm];
        const float l = Red[q * 17 + 16]        + Red[(64 + q) * 17 + 16] +
                        Red[(128 + q) * 17 + 16] + Red[(192 + q) * 17 + 16];
        Ob[base + (size_t)(q0 + q) * 1024 + fm] = f2bf(o / l);
    }
}

// -------------------------------------------------------------- launch ----
extern "C" void kernel_launch(void* const* d_in, const int* in_sizes, int n_in,
                              void* d_out, int out_size, void* d_ws, size_t ws_size,
                              hipStream_t stream) {
    const float* x  = (const float*)d_in[0];
    const float* Wq = (const float*)d_in[1];
    const float* Wk = (const float*)d_in[2];
    const float* Wv = (const float*)d_in[3];
    const float* Wo = (const float*)d_in[4];
    float* out = (float*)d_out;

    const int M = 2048, N = 1024, Kd = 1024;
    const size_t MEG = 1048576;
    unsigned short* ws = (unsigned short*)d_ws;   // 28 MB high-water
    unsigned short* xb  = ws;
    unsigned short* Wqb = ws + 2 * MEG;
    unsigned short* Wkb = ws + 3 * MEG;
    unsigned short* Wvb = ws + 4 * MEG;
    unsigned short* Wob = ws + 5 * MEG;
    unsigned short* Qb  = ws + 6 * MEG;
    unsigned short* Kb  = ws + 8 * MEG;
    unsigned short* Vb  = ws + 10 * MEG;
    unsigned short* Ob  = ws + 12 * MEG;

    dim3 gc(1024, 6, 1);
    cast_to_bf16<<<gc, 256, 0, stream>>>(x, Wq, Wk, Wv, Wo, xb, Wqb, Wkb, Wvb, Wob);

    dim3 g1(N / 128, M / 128, 3);
    gemm128_bt_mfma<<<g1, 256, 0, stream>>>(xb, Wqb, Wkb, Wvb, Qb, Kb, Vb, M, N, Kd);

    dim3 g2(2048, 1, 1);
    attn_mfma<<<g2, 256, 0, stream>>>(Qb, Kb, Vb, Ob);

    dim3 g3(N / 64, M / 64, 1);
    gemm64_bt_mfma<<<g3, 256, 0, stream>>>(Ob, Wob, out, M, N, Kd);
}

// Round 14
// 140.099 us; speedup vs baseline: 1.0094x; 1.0094x over previous
//
#include <hip/hip_runtime.h>
#include <stdint.h>
#include <math.h>

// MulHeadAttn on MI355X. B=2, C=1024, E=1024, head_dim(H)=16, n_heads(HD)=64.
// cast(fp32->bf16, Wq pre-scaled 0.25*log2e) -> fused QKV bf16-MFMA GEMM
// (128x128 tile, global_load_lds dbuf) -> MFMA flash attention
// (R22 = R20 attn body + T14 K/V register prefetch ONLY — decomposes R17's
//  bundle (prefetch + l-MFMA) which regressed attn 31->47.5us. q-tile 128,
//  grid 1024 XCD-mapped, lb(256,4). Occupancy lever falsified in R21.)
// -> bf16-MFMA O-projection (64x64 tile, 512 blocks = 2/CU).

typedef __bf16   bf16x8 __attribute__((ext_vector_type(8)));
typedef float    f32x4  __attribute__((ext_vector_type(4)));

__device__ __forceinline__ unsigned short f2bf(float f) {
    unsigned int u = __float_as_uint(f);
    u += 0x7FFFu + ((u >> 16) & 1u);         // round-to-nearest-even
    return (unsigned short)(u >> 16);
}

// async global->LDS, 16 bytes per lane (dest = wave-uniform base + lane*16)
__device__ __forceinline__ void gl16(const unsigned short* g, unsigned short* l) {
    __builtin_amdgcn_global_load_lds(
        (const __attribute__((address_space(1))) unsigned int*)g,
        (__attribute__((address_space(3))) unsigned int*)l, 16, 0, 0);
}

// ---------------------------------------------------------------- cast ----
// z=0,1: halves of x; z=2: Wq scaled 0.25*log2(e) (softmax scale folded into
// the exp2 domain); z=3..5: Wk, Wv, Wo.
__global__ __launch_bounds__(256) void cast_to_bf16(
    const float* __restrict__ x,
    const float* __restrict__ w0, const float* __restrict__ w1,
    const float* __restrict__ w2, const float* __restrict__ w3,
    unsigned short* __restrict__ xb,
    unsigned short* __restrict__ b0, unsigned short* __restrict__ b1,
    unsigned short* __restrict__ b2, unsigned short* __restrict__ b3)
{
    const int z = blockIdx.y;
    const float* src;
    unsigned short* dst;
    size_t off = 0;
    float sc = 1.f;
    if (z < 2)       { src = x;  dst = xb; off = (size_t)z << 20; }
    else if (z == 2) { src = w0; dst = b0; sc = 0.36067376022224085f; } // 0.25*log2e
    else if (z == 3) { src = w1; dst = b1; }
    else if (z == 4) { src = w2; dst = b2; }
    else             { src = w3; dst = b3; }
    const size_t i = off + ((size_t)blockIdx.x * 256 + threadIdx.x) * 4;
    const float4 v = *(const float4*)(src + i);
    *(ushort4*)(dst + i) = make_ushort4(f2bf(v.x * sc), f2bf(v.y * sc),
                                        f2bf(v.z * sc), f2bf(v.w * sc));
}

// ------------------------------------------------------- GEMM 128x128 ----
// QKV GEMM: 128x128 tile, BK=32, 4 waves each computing a 64x64 sub-tile
// via acc[4][4] of 16x16x32 MFMA. global_load_lds width-16, double-buffered.
__global__ __launch_bounds__(256) void gemm128_bt_mfma(
    const unsigned short* __restrict__ A,
    const unsigned short* __restrict__ B0, const unsigned short* __restrict__ B1,
    const unsigned short* __restrict__ B2,
    unsigned short* __restrict__ C0, unsigned short* __restrict__ C1,
    unsigned short* __restrict__ C2,
    int M, int N, int K)
{
    const unsigned short* Bm = (blockIdx.z == 0) ? B0 : (blockIdx.z == 1) ? B1 : B2;
    unsigned short* Cm       = (blockIdx.z == 0) ? C0 : (blockIdx.z == 1) ? C1 : C2;

    __shared__ __align__(16) unsigned short As[2][128 * 32];  // 16 KB
    __shared__ __align__(16) unsigned short Bs[2][128 * 32];  // 16 KB

    const int t    = threadIdx.x;
    const int lane = t & 63;
    const int w    = t >> 6;
    const int m0   = blockIdx.y * 128;
    const int n0   = blockIdx.x * 128;
    const int wm   = (w & 1) * 64;
    const int wn   = (w >> 1) * 64;

    const int r0 = t >> 2;
    const int c0 = (t & 3) * 8;
    const unsigned short* Apa = A  + (size_t)(m0 + r0) * K + c0;
    const unsigned short* Apb = Apa + (size_t)64 * K;
    const unsigned short* Bpa = Bm + (size_t)(n0 + r0) * K + c0;
    const unsigned short* Bpb = Bpa + (size_t)64 * K;
    unsigned short* lA0 = &As[0][w * 512];
    unsigned short* lA1 = &As[0][2048 + w * 512];
    unsigned short* lB0 = &Bs[0][w * 512];
    unsigned short* lB1 = &Bs[0][2048 + w * 512];
    const int bufStr = 128 * 32;

    f32x4 acc[4][4];
#pragma unroll
    for (int i = 0; i < 4; ++i)
#pragma unroll
        for (int j = 0; j < 4; ++j) acc[i][j] = (f32x4){0.f, 0.f, 0.f, 0.f};

    const int fm = lane & 15;
    const int kg = lane >> 4;

    gl16(Apa, lA0);
    gl16(Apb, lA1);
    gl16(Bpa, lB0);
    gl16(Bpb, lB1);

    int cur = 0;
    for (int k0 = 0; k0 < K; k0 += 32) {
        __syncthreads();

        if (k0 + 32 < K) {
            const int nb = (cur ^ 1);
            gl16(Apa + k0 + 32, lA0 + nb * bufStr);
            gl16(Apb + k0 + 32, lA1 + nb * bufStr);
            gl16(Bpa + k0 + 32, lB0 + nb * bufStr);
            gl16(Bpb + k0 + 32, lB1 + nb * bufStr);
        }

        const unsigned short* Ab = &As[cur][0];
        const unsigned short* Bb = &Bs[cur][0];
        bf16x8 af[4], bfr[4];
#pragma unroll
        for (int im = 0; im < 4; ++im)
            af[im] = *(const bf16x8*)&Ab[(wm + im * 16 + fm) * 32 + kg * 8];
#pragma unroll
        for (int in = 0; in < 4; ++in)
            bfr[in] = *(const bf16x8*)&Bb[(wn + in * 16 + fm) * 32 + kg * 8];
#pragma unroll
        for (int im = 0; im < 4; ++im)
#pragma unroll
            for (int in = 0; in < 4; ++in)
                acc[im][in] = __builtin_amdgcn_mfma_f32_16x16x32_bf16(
                    af[im], bfr[in], acc[im][in], 0, 0, 0);

        cur ^= 1;
    }

#pragma unroll
    for (int im = 0; im < 4; ++im) {
#pragma unroll
        for (int in = 0; in < 4; ++in) {
            const int row = m0 + wm + im * 16 + kg * 4;
            const int col = n0 + wn + in * 16 + fm;
#pragma unroll
            for (int r = 0; r < 4; ++r)
                Cm[(size_t)(row + r) * N + col] = f2bf(acc[im][in][r]);
        }
    }
}

// --------------------------------------------------------- GEMM 64x64 ----
// O-projection: 64x64 tile -> 512 blocks = 2 blocks/CU (barrier drains of
// one block overlap the other block's compute; at 1/CU they stalled the CU).
__global__ __launch_bounds__(256) void gemm64_bt_mfma(
    const unsigned short* __restrict__ A, const unsigned short* __restrict__ Bm,
    float* __restrict__ Cm, int M, int N, int K)
{
    __shared__ __align__(16) unsigned short As[2][64 * 32];   // 8 KB
    __shared__ __align__(16) unsigned short Bs[2][64 * 32];   // 8 KB

    const int t    = threadIdx.x;
    const int lane = t & 63;
    const int w    = t >> 6;
    const int m0   = blockIdx.y * 64;
    const int n0   = blockIdx.x * 64;
    const int wm   = (w & 1) * 32;
    const int wn   = (w >> 1) * 32;

    const int r0 = t >> 2;
    const int c0 = (t & 3) * 8;
    const unsigned short* Apa = A  + (size_t)(m0 + r0) * K + c0;
    const unsigned short* Bpa = Bm + (size_t)(n0 + r0) * K + c0;
    unsigned short* ldsA = &As[0][w * 512];
    unsigned short* ldsB = &Bs[0][w * 512];
    const int bufStr = 64 * 32;

    f32x4 acc[2][2];
#pragma unroll
    for (int i = 0; i < 2; ++i)
#pragma unroll
        for (int j = 0; j < 2; ++j) acc[i][j] = (f32x4){0.f, 0.f, 0.f, 0.f};

    const int fm = lane & 15;
    const int kg = lane >> 4;

    gl16(Apa, ldsA);
    gl16(Bpa, ldsB);

    int cur = 0;
    for (int k0 = 0; k0 < K; k0 += 32) {
        __syncthreads();

        if (k0 + 32 < K) {
            const int nb = (cur ^ 1);
            gl16(Apa + k0 + 32, ldsA + nb * bufStr);
            gl16(Bpa + k0 + 32, ldsB + nb * bufStr);
        }

        const unsigned short* Ab = &As[cur][0];
        const unsigned short* Bb = &Bs[cur][0];
        bf16x8 af[2], bfr[2];
#pragma unroll
        for (int im = 0; im < 2; ++im)
            af[im] = *(const bf16x8*)&Ab[(wm + im * 16 + fm) * 32 + kg * 8];
#pragma unroll
        for (int in = 0; in < 2; ++in)
            bfr[in] = *(const bf16x8*)&Bb[(wn + in * 16 + fm) * 32 + kg * 8];
#pragma unroll
        for (int im = 0; im < 2; ++im)
#pragma unroll
            for (int in = 0; in < 2; ++in)
                acc[im][in] = __builtin_amdgcn_mfma_f32_16x16x32_bf16(
                    af[im], bfr[in], acc[im][in], 0, 0, 0);

        cur ^= 1;
    }

#pragma unroll
    for (int im = 0; im < 2; ++im) {
#pragma unroll
        for (int in = 0; in < 2; ++in) {
            const int row = m0 + wm + im * 16 + kg * 4;
            const int col = n0 + wn + in * 16 + fm;
#pragma unroll
            for (int r = 0; r < 4; ++r)
                Cm[(size_t)(row + r) * N + col] = acc[im][in][r];
        }
    }
}

// ----------------------------------------------------------- attention ----
// R22: R20 body (keys-split, q-tile 128, grid 1024 XCD-mapped, 4 blocks/CU,
// barrier-free k-loop, P-in-register via permuted key axis) + T14 prefetch
// ONLY: tile t+1's K/V global loads issue before tile t's m-loop (~600 cyc
// of compute covers the load latency; the vmcnt wait lands at the next
// iteration's ds_write). lp stays a VALU sum (no l-MFMA — R17 decomposition).
#define KROWS 40    // Ks row stride (u16): 16 real d + 24 pad (80 B)
#define VROWS 72    // VsT row stride (u16): 32 perm cols + 40 pad (144 B)

__global__ __launch_bounds__(256, 4) void attn_mfma(
    const unsigned short* __restrict__ Qb, const unsigned short* __restrict__ Kb,
    const unsigned short* __restrict__ Vb, unsigned short* __restrict__ Ob)
{
    // per-wave: Ks 2560 B @ wv*2560 | VsT 2304 B @ 10240+wv*2304 (19456 B live)
    // Red overlay (after final barrier): float[512][17] = 34816 B
    __shared__ __align__(16) unsigned char smem[34816];

    const int t    = threadIdx.x;
    const int lane = t & 63;
    const int wv   = t >> 6;
    const int fm   = lane & 15;
    const int kg   = lane >> 4;

    // XCD-aware inverse mapping: blk = xcd + 8*i round-robins across XCDs.
    const int blk = blockIdx.x;
    const int xcd = blk & 7;
    const int i_  = blk >> 3;
    const int qt  = i_ & 7;
    const int hdg = (i_ >> 3) & 3;
    const int gs  = (i_ >> 5) & 1;
    const int bb  = (i_ >> 6) & 1;
    const int hd  = (xcd + gs * 8) * 4 + hdg;
    const size_t base = ((size_t)bb << 20) + (size_t)hd * 16;
    const int q0 = qt * 128;
    const int wk = wv * 32;          // wave's key offset within tile

    unsigned short* Ks  = (unsigned short*)(smem + wv * 2560);
    unsigned short* VsT = (unsigned short*)(smem + 10240 + wv * 2304);
    float*          Red = (float*)smem;

    // staging roles: lane covers (key2 = lane>>1, half = lane&1)
    const int key2 = lane >> 1, half = lane & 1;
    // permuted V column for key2: slot where PV expects this key
    const int vcol = ((key2 & 15) >> 2) * 8 + (key2 & 3) + ((key2 >> 4) << 2);

    // Q fragments (B-operand): row q0+m*16+fm, k=kg*8 (zero for kg>=2)
    union { uint4 u; bf16x8 h; } zz; zz.u = make_uint4(0, 0, 0, 0);
    bf16x8 aq[8];
#pragma unroll
    for (int m = 0; m < 8; ++m) {
        if (kg < 2)
            aq[m] = *(const bf16x8*)(Qb + base +
                     (size_t)(q0 + m * 16 + fm) * 1024 + kg * 8);
        else
            aq[m] = zz.h;
    }

    f32x4 oacc[8];
    float lp[8];
#pragma unroll
    for (int m = 0; m < 8; ++m) {
        oacc[m] = (f32x4){0.f, 0.f, 0.f, 0.f};
        lp[m] = 0.f;
    }

    // prologue: prefetch tile 0's K/V into registers
    uint4 kd = *(const uint4*)(Kb + base + (size_t)(wk + key2) * 1024 + half * 8);
    uint4 vd = *(const uint4*)(Vb + base + (size_t)(wk + key2) * 1024 + half * 8);

    for (int kt = 0; kt < 1024; kt += 128) {
        // ---- write prefetched K/V regs to LDS (wave-private)
        {
            *(uint4*)&Ks[key2 * KROWS + half * 8] = kd;
            const unsigned short* pv = (const unsigned short*)&vd;
#pragma unroll
            for (int d = 0; d < 8; ++d)
                VsT[(half * 8 + d) * VROWS + vcol] = pv[d];
        }

        // ---- K fragments (A-operand) from LDS: row fm / 16+fm, k=kg*8
        bf16x8 bk0 = zz.h, bk1 = zz.h;
        if (kg < 2) {
            bk0 = *(const bf16x8*)&Ks[fm * KROWS + kg * 8];
            bk1 = *(const bf16x8*)&Ks[(16 + fm) * KROWS + kg * 8];
        }

        // ---- V fragment (B-operand, perm cols): row d=fm, slots kg*8..+8
        const bf16x8 bv = *(const bf16x8*)&VsT[fm * VROWS + kg * 8];

        // ---- T14: issue tile t+1's K/V loads before the compute phase
        if (kt + 128 < 1024) {
            kd = *(const uint4*)(Kb + base +
                  (size_t)(kt + 128 + wk + key2) * 1024 + half * 8);
            vd = *(const uint4*)(Vb + base +
                  (size_t)(kt + 128 + wk + key2) * 1024 + half * 8);
        }

        // ---- QK -> exp2 -> in-register P -> PV (all per-lane)
#pragma unroll
        for (int m = 0; m < 8; ++m) {
            f32x4 s0 = __builtin_amdgcn_mfma_f32_16x16x32_bf16(
                bk0, aq[m], (f32x4){0.f, 0.f, 0.f, 0.f}, 0, 0, 0);
            f32x4 s1 = __builtin_amdgcn_mfma_f32_16x16x32_bf16(
                bk1, aq[m], (f32x4){0.f, 0.f, 0.f, 0.f}, 0, 0, 0);
            const float p0 = __builtin_amdgcn_exp2f(s0[0]);
            const float p1 = __builtin_amdgcn_exp2f(s0[1]);
            const float p2 = __builtin_amdgcn_exp2f(s0[2]);
            const float p3 = __builtin_amdgcn_exp2f(s0[3]);
            const float p4 = __builtin_amdgcn_exp2f(s1[0]);
            const float p5 = __builtin_amdgcn_exp2f(s1[1]);
            const float p6 = __builtin_amdgcn_exp2f(s1[2]);
            const float p7 = __builtin_amdgcn_exp2f(s1[3]);
            lp[m] += ((p0 + p1) + (p2 + p3)) + ((p4 + p5) + (p6 + p7));
            bf16x8 aph;
            aph[0] = (__bf16)p0; aph[1] = (__bf16)p1;
            aph[2] = (__bf16)p2; aph[3] = (__bf16)p3;
            aph[4] = (__bf16)p4; aph[5] = (__bf16)p5;
            aph[6] = (__bf16)p6; aph[7] = (__bf16)p7;
            oacc[m] = __builtin_amdgcn_mfma_f32_16x16x32_bf16(
                aph, bv, oacc[m], 0, 0, 0);
        }
    }

    // l: sum the 4 kg-group partials -> every lane holds l_wave[q=m*16+fm]
#pragma unroll
    for (int m = 0; m < 8; ++m) {
        lp[m] += __shfl_xor(lp[m], 16, 64);
        lp[m] += __shfl_xor(lp[m], 32, 64);
    }

    __syncthreads();   // all waves done with Ks/VsT -> overlay Red
#pragma unroll
    for (int m = 0; m < 8; ++m) {
#pragma unroll
        for (int r = 0; r < 4; ++r)
            Red[((wv * 128) + m * 16 + kg * 4 + r) * 17 + fm] = oacc[m][r];
        if (kg == 0)
            Red[((wv * 128) + m * 16 + fm) * 17 + 16] = lp[m];
    }
    __syncthreads();

    // wave wv finalizes q-rows [wv*32, wv*32+32)
#pragma unroll
    for (int mp = 0; mp < 2; ++mp) {
#pragma unroll
        for (int r = 0; r < 4; ++r) {
            const int q = wv * 32 + mp * 16 + kg * 4 + r;
            const float o = Red[q * 17 + fm]         + Red[(128 + q) * 17 + fm] +
                            Red[(256 + q) * 17 + fm] + Red[(384 + q) * 17 + fm];
            const float l = Red[q * 17 + 16]         + Red[(128 + q) * 17 + 16] +
                            Red[(256 + q) * 17 + 16] + Red[(384 + q) * 17 + 16];
            Ob[base + (size_t)(q0 + q) * 1024 + fm] = f2bf(o / l);
        }
    }
}

// -------------------------------------------------------------- launch ----
extern "C" void kernel_launch(void* const* d_in, const int* in_sizes, int n_in,
                              void* d_out, int out_size, void* d_ws, size_t ws_size,
                              hipStream_t stream) {
    const float* x  = (const float*)d_in[0];
    const float* Wq = (const float*)d_in[1];
    const float* Wk = (const float*)d_in[2];
    const float* Wv = (const float*)d_in[3];
    const float* Wo = (const float*)d_in[4];
    float* out = (float*)d_out;

    const int M = 2048, N = 1024, Kd = 1024;
    const size_t MEG = 1048576;
    unsigned short* ws = (unsigned short*)d_ws;   // 28 MB high-water
    unsigned short* xb  = ws;
    unsigned short* Wqb = ws + 2 * MEG;
    unsigned short* Wkb = ws + 3 * MEG;
    unsigned short* Wvb = ws + 4 * MEG;
    unsigned short* Wob = ws + 5 * MEG;
    unsigned short* Qb  = ws + 6 * MEG;
    unsigned short* Kb  = ws + 8 * MEG;
    unsigned short* Vb  = ws + 10 * MEG;
    unsigned short* Ob  = ws + 12 * MEG;

    dim3 gc(1024, 6, 1);
    cast_to_bf16<<<gc, 256, 0, stream>>>(x, Wq, Wk, Wv, Wo, xb, Wqb, Wkb, Wvb, Wob);

    dim3 g1(N / 128, M / 128, 3);
    gemm128_bt_mfma<<<g1, 256, 0, stream>>>(xb, Wqb, Wkb, Wvb, Qb, Kb, Vb, M, N, Kd);

    dim3 g2(1024, 1, 1);
    attn_mfma<<<g2, 256, 0, stream>>>(Qb, Kb, Vb, Ob);

    dim3 g3(N / 64, M / 64, 1);
    gemm64_bt_mfma<<<g3, 256, 0, stream>>>(Ob, Wob, out, M, N, Kd);
}